// Round 2
// baseline (382.155 us; speedup 1.0000x reference)
//
#include <hip/hip_runtime.h>

#define B_    8
#define T_    512
#define D_    768
#define L_    16
#define DL_   128
#define M_    4096   // B_*T_
#define BN_EPS 1e-5f

typedef __attribute__((ext_vector_type(8))) short short8;
typedef __attribute__((ext_vector_type(4))) float f32x4;

__device__ inline unsigned short f2bf(float x) {
    unsigned int u = __float_as_uint(x);
    return (unsigned short)((u + 0x7fffu + ((u >> 16) & 1u)) >> 16);
}

// async global->LDS, 16B per lane. LDS dest is wave-uniform base + lane*16.
__device__ inline void async16(const unsigned short* gptr, unsigned short* lptr) {
    __builtin_amdgcn_global_load_lds(
        (const __attribute__((address_space(1))) void*)gptr,
        (__attribute__((address_space(3))) void*)lptr, 16, 0, 0);
}

// ---------------- Kernel 1: masked per-channel sum / sumsq / count ----------
// grid 256 x 256, 16 tokens per block. stats floats:
// [0..767]=sum, [768..1535]=sumsq, [1536]=cnt, [2048..2815]=scale, [2816..3583]=shift
__global__ void k_stats(const float* __restrict__ f, const int* __restrict__ mask,
                        float* __restrict__ stats) {
    int tid = threadIdx.x;
    int t0  = blockIdx.x * 16;
    float s0 = 0.f, s1 = 0.f, s2 = 0.f, q0 = 0.f, q1 = 0.f, q2 = 0.f;
    for (int tt = 0; tt < 16; ++tt) {
        int t = t0 + tt;
        float m = mask[t] ? 1.f : 0.f;
        const float* row = f + (size_t)t * D_;
        float x0 = row[tid];
        float x1 = row[tid + 256];
        float x2 = row[tid + 512];
        s0 += x0 * m; q0 += x0 * x0 * m;
        s1 += x1 * m; q1 += x1 * x1 * m;
        s2 += x2 * m; q2 += x2 * x2 * m;
    }
    atomicAdd(&stats[tid      ], s0);
    atomicAdd(&stats[tid + 256], s1);
    atomicAdd(&stats[tid + 512], s2);
    atomicAdd(&stats[768 + tid      ], q0);
    atomicAdd(&stats[768 + tid + 256], q1);
    atomicAdd(&stats[768 + tid + 512], q2);
    if (tid == 0) {
        int c = 0;
        for (int tt = 0; tt < 16; ++tt) c += (mask[t0 + tt] ? 1 : 0);
        atomicAdd(&stats[1536], (float)c);
    }
}

// ---------------- Kernel 1b: finalize scale/shift ---------------------------
__global__ void k_finalize(const float* __restrict__ gamma, const float* __restrict__ beta,
                           float* __restrict__ stats) {
    int d = threadIdx.x;  // 768
    float denom = fmaxf(stats[1536], 1.f);
    float mean  = stats[d] / denom;
    float var   = fmaxf(stats[768 + d] / denom - mean * mean, 0.f);
    float sc    = gamma[d] * rsqrtf(var + BN_EPS);
    stats[2048 + d] = sc;
    stats[2816 + d] = beta[d] - mean * sc;
}

// ---------------- Kernel 2: norm+cast feats, and cast+permute ff_w ----------
// blocks [0,3072): normalize features -> bf16 feats
// blocks [3072,6144): cast ff_w row o -> permuted row nr = c*2048 + l*128 + d
//   (o = l*256 + d*2 + c), so FFN column tiles become (c,l)-uniform.
__global__ void k_prep(const float4* __restrict__ f4, const int* __restrict__ mask,
                       const float* __restrict__ stats, unsigned short* __restrict__ feats,
                       const float4* __restrict__ w4, unsigned short* __restrict__ wbf) {
    int bx = blockIdx.x;
    if (bx < 3072) {
        int i  = bx * 256 + threadIdx.x;      // over M_*D_/4
        int d4 = i % (D_ / 4);
        int t  = i / (D_ / 4);
        float m = mask[t] ? 1.f : 0.f;
        float4 v = f4[i];
        int d = d4 * 4;
        ushort4 o;
        o.x = f2bf((v.x * stats[2048 + d + 0] + stats[2816 + d + 0]) * m);
        o.y = f2bf((v.y * stats[2048 + d + 1] + stats[2816 + d + 1]) * m);
        o.z = f2bf((v.z * stats[2048 + d + 2] + stats[2816 + d + 2]) * m);
        o.w = f2bf((v.w * stats[2048 + d + 3] + stats[2816 + d + 3]) * m);
        ((ushort4*)feats)[i] = o;
    } else {
        int i  = (bx - 3072) * 256 + threadIdx.x;  // over 4096*192
        int o  = i / 192, cg = i % 192;
        int nr = (o & 1) * 2048 + (o >> 8) * 128 + ((o >> 1) & 127);
        float4 v = w4[i];
        ushort4 u;
        u.x = f2bf(v.x); u.y = f2bf(v.y); u.z = f2bf(v.z); u.w = f2bf(v.w);
        ((ushort4*)wbf)[nr * 192 + cg] = u;
    }
}

// ---------------- Kernel 3: FFN GEMM (h = relu(feats @ Wperm^T + b)) --------
// A[4096][768] bf16, Wperm[4096][768] bf16. 128x128 tile / 256 threads.
// Column tile bn is exactly one (c = bn>>4, l = bn&15) pair; epilogue writes
// bf16 into start/end arrays laid out [B][L][T][DL].
__launch_bounds__(256)
__global__ void k_ffn(const unsigned short* __restrict__ A, const unsigned short* __restrict__ W,
                      const float* __restrict__ ffb,
                      unsigned short* __restrict__ startp, unsigned short* __restrict__ endp) {
    __shared__ alignas(16) unsigned short As[128 * 32];
    __shared__ alignas(16) unsigned short Bs[128 * 32];
    int tid  = threadIdx.x;
    int bm   = blockIdx.x, bn = blockIdx.y;
    int wave = tid >> 6, lane = tid & 63;
    int wm = wave >> 1, wn = wave & 1;
    int lr = lane & 15, quad = lane >> 4;
    int srow = lane >> 2, sseg = (lane & 3) * 8;
    f32x4 acc[4][4] = {};
    const int K = D_;
    const unsigned short* Abase = A + (size_t)(bm * 128) * K;
    const unsigned short* Wbase = W + (size_t)(bn * 128) * K;
    for (int k0 = 0; k0 < K; k0 += 32) {
#pragma unroll
        for (int p = 0; p < 2; ++p) {
            int r0 = (wave * 2 + p) * 16;
            async16(Abase + (size_t)(r0 + srow) * K + k0 + sseg, &As[r0 * 32]);
            async16(Wbase + (size_t)(r0 + srow) * K + k0 + sseg, &Bs[r0 * 32]);
        }
        __syncthreads();
        short8 a[4], b[4];
#pragma unroll
        for (int i = 0; i < 4; ++i) a[i] = *(const short8*)&As[(wm * 64 + i * 16 + lr) * 32 + quad * 8];
#pragma unroll
        for (int i = 0; i < 4; ++i) b[i] = *(const short8*)&Bs[(wn * 64 + i * 16 + lr) * 32 + quad * 8];
#pragma unroll
        for (int i = 0; i < 4; ++i)
#pragma unroll
            for (int j = 0; j < 4; ++j)
                acc[i][j] = __builtin_amdgcn_mfma_f32_16x16x32_bf16(a[i], b[j], acc[i][j], 0, 0, 0);
        __syncthreads();
    }
    // epilogue: col' = bn*128 + wn*64 + j*16 + lr; c=bn>>4, l=bn&15 (uniform)
    int c = bn >> 4, l = bn & 15;
    unsigned short* dstb = c ? endp : startp;
#pragma unroll
    for (int j = 0; j < 4; ++j) {
        int dd = wn * 64 + j * 16 + lr;
        float bv = ffb[l * 256 + dd * 2 + c];
#pragma unroll
        for (int i = 0; i < 4; ++i) {
#pragma unroll
            for (int r = 0; r < 4; ++r) {
                int row = bm * 128 + wm * 64 + i * 16 + quad * 4 + r;  // token
                int bb = row >> 9, tt = row & 511;
                float v = fmaxf(acc[i][j][r] + bv, 0.f);
                dstb[(((size_t)(bb * 16 + l) * 512 + tt) << 7) + dd] = f2bf(v);
            }
        }
    }
}

// ---------------- Kernel 4: biaffine scores + fused spans_mask --------------
// per (b,l): S[s,e] = sum_d start[s,d]*end[e,d] + label_bias[l]
//            M[s,e] = (s<=e) && mask[b,s] && mask[b,e]
// grid (4,4,128), block 256
__launch_bounds__(256)
__global__ void k_biaffine(const unsigned short* __restrict__ startp,
                           const unsigned short* __restrict__ endp,
                           const float* __restrict__ lbias, const int* __restrict__ mask,
                           float* __restrict__ outs, float* __restrict__ outm) {
    __shared__ alignas(16) unsigned short As[128 * 32];
    __shared__ alignas(16) unsigned short Bs[128 * 32];
    int tid = threadIdx.x;
    int bm = blockIdx.x, bn = blockIdx.y;
    int bl = blockIdx.z;  // b*16 + l
    int b  = bl >> 4;
    const unsigned short* Abase = startp + ((size_t)bl * 512 + bm * 128) * 128;
    const unsigned short* Bbase = endp   + ((size_t)bl * 512 + bn * 128) * 128;
    int wave = tid >> 6, lane = tid & 63;
    int wm = wave >> 1, wn = wave & 1;
    int lr = lane & 15, quad = lane >> 4;
    int srow = lane >> 2, sseg = (lane & 3) * 8;
    f32x4 acc[4][4] = {};
    for (int k0 = 0; k0 < 128; k0 += 32) {
#pragma unroll
        for (int p = 0; p < 2; ++p) {
            int r0 = (wave * 2 + p) * 16;
            async16(Abase + (size_t)(r0 + srow) * 128 + k0 + sseg, &As[r0 * 32]);
            async16(Bbase + (size_t)(r0 + srow) * 128 + k0 + sseg, &Bs[r0 * 32]);
        }
        __syncthreads();
        short8 a[4], b8[4];
#pragma unroll
        for (int i = 0; i < 4; ++i) a[i]  = *(const short8*)&As[(wm * 64 + i * 16 + lr) * 32 + quad * 8];
#pragma unroll
        for (int i = 0; i < 4; ++i) b8[i] = *(const short8*)&Bs[(wn * 64 + i * 16 + lr) * 32 + quad * 8];
#pragma unroll
        for (int i = 0; i < 4; ++i)
#pragma unroll
            for (int j = 0; j < 4; ++j)
                acc[i][j] = __builtin_amdgcn_mfma_f32_16x16x32_bf16(a[i], b8[j], acc[i][j], 0, 0, 0);
        __syncthreads();
    }
    float lb = lbias[bl & 15];
    float* os = outs + (size_t)bl * 262144;
    float* om = outm + (size_t)bl * 262144;
#pragma unroll
    for (int i = 0; i < 4; ++i) {
#pragma unroll
        for (int r = 0; r < 4; ++r) {
            int s = bm * 128 + wm * 64 + i * 16 + quad * 4 + r;
            float msv = mask[b * 512 + s] ? 1.f : 0.f;
#pragma unroll
            for (int j = 0; j < 4; ++j) {
                int e = bn * 128 + wn * 64 + j * 16 + lr;
                os[(size_t)s * 512 + e] = acc[i][j][r] + lb;
                om[(size_t)s * 512 + e] = (s <= e && mask[b * 512 + e]) ? msv : 0.f;
            }
        }
    }
}

extern "C" void kernel_launch(void* const* d_in, const int* in_sizes, int n_in,
                              void* d_out, int out_size, void* d_ws, size_t ws_size,
                              hipStream_t stream) {
    const float* features = (const float*)d_in[0];
    const int*   mask     = (const int*)d_in[1];
    const float* gamma    = (const float*)d_in[2];
    const float* beta     = (const float*)d_in[3];
    const float* ffw      = (const float*)d_in[4];
    const float* ffb      = (const float*)d_in[5];
    const float* lbias    = (const float*)d_in[6];

    float* out_scores = (float*)d_out;
    float* out_mask   = out_scores + (size_t)B_ * L_ * T_ * T_;  // 33554432

    char* ws = (char*)d_ws;
    float*          stats  = (float*)ws;                              // 16 KiB
    unsigned short* feats  = (unsigned short*)(ws + 16384);           // 6 MiB
    unsigned short* wbf    = (unsigned short*)(ws + 16384 + 6291456); // 6 MiB
    unsigned short* startp = (unsigned short*)(ws + 12599296);        // 16 MiB
    unsigned short* endp   = (unsigned short*)(ws + 29376512);        // 16 MiB

    hipMemsetAsync(ws, 0, 16384, stream);
    k_stats<<<256, 256, 0, stream>>>(features, mask, stats);
    k_finalize<<<1, 768, 0, stream>>>(gamma, beta, stats);
    k_prep<<<6144, 256, 0, stream>>>((const float4*)features, mask, stats, feats,
                                     (const float4*)ffw, wbf);
    dim3 g1(32, 32);
    k_ffn<<<g1, 256, 0, stream>>>(feats, wbf, ffb, startp, endp);
    dim3 g2(4, 4, 128);
    k_biaffine<<<g2, 256, 0, stream>>>(startp, endp, lbias, mask, out_scores, out_mask);
}